// Round 5
// baseline (181.123 us; speedup 1.0000x reference)
//
#include <hip/hip_runtime.h>
#include <math.h>

// PizzaBurningEffect: out = clip(img * (1 - bm*(1-dark_scale_c)), 0, 1)
// bm = clip(max(ew_norm, max_s spot_s) * burn, 0, 1), shared across C=3 channels.
//
// R4 post-mortem: 59.9us @ 2.5 TB/s, VALUBusy 31%, VGPR=32 -> latency-bound:
// compiler serialized load->wait->compute->store per channel. This round:
// 8 px/thread, all 6 float4 loads issued BEFORE mask compute (ILP), row-folded
// spot params (3 regs/spot), rcp for the radius divide, plain cached stores.

namespace {
constexpr int B = 32, C = 3, H = 512, W = 512, S = 8;
constexpr int PLANE = H * W;                      // 262144
constexpr int PIX8_PER_BATCH = PLANE / 8;         // 32768 float8 per plane
constexpr int BLOCKS_PER_BATCH = PIX8_PER_BATCH / 256;  // 128
constexpr float LOG2E = 1.4426950408889634f;
typedef float fvec4 __attribute__((ext_vector_type(4)));
}

__global__ __launch_bounds__(256) void pizza_burn_kernel(
    const float* __restrict__ img,
    const float* __restrict__ u_xy,
    const float* __restrict__ u_radius,
    const float* __restrict__ u_intensity,
    const float* __restrict__ u_burn,
    float* __restrict__ out,
    const float ew_scale, const float ew_bias)
{
  // b is wave-uniform (derived from blockIdx only) -> spot params scalarize.
  const int b    = blockIdx.x >> 7;                         // 128 blocks per batch
  const int pix8 = ((blockIdx.x & 127) << 8) | threadIdx.x; // 0..32767
  const int h    = pix8 >> 6;            // 64 float8 per row of 512
  const int w0   = (pix8 & 63) << 3;     // starting column of this float8

  // Issue ALL image loads first: 6 x global_load_dwordx4 in flight while the
  // ~1000-cycle mask computation runs -> HBM latency fully hidden.
  const size_t base = (size_t)b * (C * PLANE) + (size_t)h * W + w0;
  fvec4 v[6];
#pragma unroll
  for (int c = 0; c < C; ++c) {
    v[2 * c + 0] = *reinterpret_cast<const fvec4*>(img + base + (size_t)c * PLANE);
    v[2 * c + 1] = *reinterpret_cast<const fvec4*>(img + base + (size_t)c * PLANE + 4);
  }

  const float delta = 2.0f / 511.0f;
  const float yc = fmaf((float)h, delta, -1.0f);
  const float y2 = yc * yc;

  // Per-batch spot parameters (uniform across the block). All 8 pixels share
  // yc, so fold the y-term: lm_s(x) = nc_s*(xc-sx_s)^2 + cy_s,
  // cy_s = nc_s*(yc-sy_s)^2 + log2(si_s).   3 regs/spot.
  const float* uxy = u_xy        + (size_t)b * S * 2;
  const float* urd = u_radius    + (size_t)b * S;
  const float* uin = u_intensity + (size_t)b * S;
  float sx[S], nc[S], cy[S];
#pragma unroll
  for (int s = 0; s < S; ++s) {
    sx[s] = fmaf(2.0f, uxy[2 * s + 0], -1.0f);
    const float sy = fmaf(2.0f, uxy[2 * s + 1], -1.0f);
    const float r  = fmaf(0.15f, urd[s], 0.05f);
    // nc = -log2(e) / (2 r^2)  via 1-ulp v_rcp (tolerance 4e-3 >> rcp error)
    nc[s] = (-0.5f * LOG2E) * __builtin_amdgcn_rcpf(r * r);
    const float lsi = __builtin_amdgcn_logf(fmaf(0.5f, uin[s], 0.5f)); // log2(si)
    const float dy  = yc - sy;
    cy[s] = fmaf(nc[s] * dy, dy, lsi);
  }
  const float burn = fmaf(0.6f, u_burn[b], 0.2f);      // BURN_MIN + 0.6*u

  // Burn mask for 8 consecutive pixels (same row), reused across 3 channels.
  float bm[8];
#pragma unroll
  for (int j = 0; j < 8; ++j) {
    const float xc   = fmaf((float)(w0 + j), delta, -1.0f);
    const float dist = __builtin_amdgcn_sqrtf(fmaf(xc, xc, y2));
    const float ew   = __builtin_amdgcn_exp2f(fmaf(dist, 2.0f * LOG2E, -1.4f * LOG2E));
    const float ewn  = fmaf(ew, ew_scale, ew_bias);    // (ew - ew_min) * inv_range
    float lm = -3.0e38f;
#pragma unroll
    for (int s = 0; s < S; ++s) {
      const float t = xc - sx[s];
      lm = fmaxf(lm, fmaf(nc[s] * t, t, cy[s]));       // log2(spot_s)
    }
    const float spots = __builtin_amdgcn_exp2f(lm);
    bm[j] = fminf(fmaxf(fmaxf(ewn, spots) * burn, 0.0f), 1.0f);
  }

  // out = clip(img * (1 - bm*(1-ds_c)), 0, 1), two 16B stores per channel.
  const float omds[3] = {1.0f - 0.7f, 1.0f - 0.4f, 1.0f - 0.3f};
#pragma unroll
  for (int c = 0; c < C; ++c) {
    const float k = omds[c];
    fvec4 o0, o1;
    o0.x = fminf(fmaxf(v[2*c].x   * fmaf(-bm[0], k, 1.0f), 0.0f), 1.0f);
    o0.y = fminf(fmaxf(v[2*c].y   * fmaf(-bm[1], k, 1.0f), 0.0f), 1.0f);
    o0.z = fminf(fmaxf(v[2*c].z   * fmaf(-bm[2], k, 1.0f), 0.0f), 1.0f);
    o0.w = fminf(fmaxf(v[2*c].w   * fmaf(-bm[3], k, 1.0f), 0.0f), 1.0f);
    o1.x = fminf(fmaxf(v[2*c+1].x * fmaf(-bm[4], k, 1.0f), 0.0f), 1.0f);
    o1.y = fminf(fmaxf(v[2*c+1].y * fmaf(-bm[5], k, 1.0f), 0.0f), 1.0f);
    o1.z = fminf(fmaxf(v[2*c+1].z * fmaf(-bm[6], k, 1.0f), 0.0f), 1.0f);
    o1.w = fminf(fmaxf(v[2*c+1].w * fmaf(-bm[7], k, 1.0f), 0.0f), 1.0f);
    *reinterpret_cast<fvec4*>(out + base + (size_t)c * PLANE)     = o0;
    *reinterpret_cast<fvec4*>(out + base + (size_t)c * PLANE + 4) = o1;
  }
}

extern "C" void kernel_launch(void* const* d_in, const int* in_sizes, int n_in,
                              void* d_out, int out_size, void* d_ws, size_t ws_size,
                              hipStream_t stream) {
  const float* img         = (const float*)d_in[0];
  const float* u_xy        = (const float*)d_in[1];
  const float* u_radius    = (const float*)d_in[2];
  const float* u_intensity = (const float*)d_in[3];
  const float* u_burn      = (const float*)d_in[4];
  float* out = (float*)d_out;

  // ew min/max analytic: exp is monotone in dist.
  // min dist at grid point (±1/511, ±1/511), max at the corners (±1, ±1).
  const float delta = 2.0f / 511.0f;
  const float cmin  = fabsf(-1.0f + 255.0f * delta);   // ~= 1/511 in f32 linspace arithmetic
  const float dmin  = sqrtf(2.0f * cmin * cmin);
  const float dmax  = sqrtf(2.0f);
  const float ew_min = expf(2.0f * (dmin - 0.7f));
  const float ew_max = expf(2.0f * (dmax - 0.7f));
  const float inv_range = 1.0f / (ew_max - ew_min + 1e-6f);
  const float ew_bias = -ew_min * inv_range;

  dim3 grid(B * BLOCKS_PER_BATCH);  // 4096 blocks
  dim3 block(256);
  pizza_burn_kernel<<<grid, block, 0, stream>>>(img, u_xy, u_radius, u_intensity,
                                                u_burn, out, inv_range, ew_bias);
}